// Round 8
// baseline (339.739 us; speedup 1.0000x reference)
//
#include <hip/hip_runtime.h>
#include <stdint.h>

// ---------------------------------------------------------------------------
// EdgeNodeGCN on MI355X (gfx950). Inputs fp32, edge_index int32, output fp32.
// Factorization:
//   P[n]  = x[n] @ (Wa - Wb) + b_edge   (Wa = W_edge[0:128], Wb = W_edge[128:256])
//   Q[n]  = x[n] @ Wb
//   msg(e)= relu(P[dst] + Q[src]);  edge_agg[d] = sum msg  (pull via CSR)
//   XA[d] = sum_{e->d} x[src]           (segment_sum commutes with @W_node)
//   nodes = relu(XA @ W_node + b_node); edges = relu(edge_agg @ W_ed + b_ed)
//   out   = sigmoid(relu([nodes|edges] @ W_f1 + b_f1) @ W_f2 + b_f2)
//
// R8 vs R7 (322 us; k_sg 80us, all pipes idle):
//   - k_sg C-write: LDS-staged double-buffer -> coalesced us4 stores
//     (was 64 scalar u16 stores/wave-tile in 32B fragments; WRITE 68MB vs
//      52MB payload)
//   - weights stored TRANSPOSED (col-major) by k_convert -> B-fragments are
//     single short8 vector loads (was per-lane scalar u16: ~512 VMEM
//     instrs/wave in k_tail)
//   - k_gather: 2x unroll -> 4 edges in flight per iteration
// ---------------------------------------------------------------------------

typedef short short8 __attribute__((ext_vector_type(8)));
typedef float f32x4 __attribute__((ext_vector_type(4)));
typedef float float4v __attribute__((ext_vector_type(4)));
typedef unsigned short us8 __attribute__((ext_vector_type(8)));
typedef unsigned short us4 __attribute__((ext_vector_type(4)));

__device__ inline float bf2f(unsigned short h) {
    union { unsigned int u; float f; } v;
    v.u = ((unsigned int)h) << 16;
    return v.f;
}
__device__ inline unsigned short f2bf(float f) {
    union { float f; unsigned int u; } v;
    v.f = f;
    unsigned int r = v.u + 0x7FFFu + ((v.u >> 16) & 1u);  // RNE
    return (unsigned short)(r >> 16);
}

// ---- convert x + weights(BT, col-major) -> bf16; zero deg/counter ---------
__global__ __launch_bounds__(256) void k_convert(
    const float* __restrict__ x, const float* __restrict__ W_edge,
    const float* __restrict__ W_node, const float* __restrict__ W_ed,
    const float* __restrict__ W_f1,
    unsigned short* __restrict__ xb, unsigned short* __restrict__ WE2T,
    unsigned short* __restrict__ WnT, unsigned short* __restrict__ WdT,
    unsigned short* __restrict__ Wf1T, int* __restrict__ deg,
    int quads, int nzero)
{
    int i = blockIdx.x * 256 + threadIdx.x;
    if (i < quads) {
        float4v v = ((const float4v*)x)[i];
        us4 o;
        for (int j = 0; j < 4; ++j) o[j] = f2bf(v[j]);
        ((us4*)xb)[i] = o;
        return;
    }
    int j = i - quads;
    if (j < 65536) {                          // WE2T [512 c][128 k] = [Wa-Wb|Wb]^T
        int c = j & 511, k = j >> 9;
        float v;
        if (c < 256) v = W_edge[k * 256 + c] - W_edge[(k + 128) * 256 + c];
        else         v = W_edge[(k + 128) * 256 + (c - 256)];
        WE2T[c * 128 + k] = f2bf(v);
    } else if (j < 65536 + 32768) {           // WnT [256 c][128 k]
        int t = j - 65536;
        int c = t & 255, k = t >> 8;
        WnT[c * 128 + k] = f2bf(W_node[k * 256 + c]);
    } else if (j < 65536 + 65536) {           // WdT [128 c][256 k]
        int t = j - 65536 - 32768;
        int c = t & 127, k = t >> 7;
        WdT[c * 256 + k] = f2bf(W_ed[k * 128 + c]);
    } else if (j < 143360) {                  // Wf1T [32 c][384 k]
        int t = j - 65536 - 65536;
        int c = t & 31, k = t >> 5;
        Wf1T[c * 384 + k] = f2bf(W_f1[k * 32 + c]);
    } else {
        int t = j - 143360;
        if (t < nzero) deg[t] = 0;            // deg[N] + counter
    }
}

// ---- CSR build ------------------------------------------------------------
__global__ void k_hist(const int* __restrict__ dst, int* __restrict__ deg,
                       int E, int N) {
    int i = blockIdx.x * 256 + threadIdx.x;
    if (i >= E) return;
    int d = dst[i];
    if ((unsigned)d < (unsigned)N) atomicAdd(&deg[d], 1);
}

// start[n] via wave-level exclusive scan + one atomicAdd per wave.
__global__ __launch_bounds__(256) void k_assign(
    int* __restrict__ deg_cursor, int* __restrict__ startv,
    int* __restrict__ counter, int N)
{
    int n = blockIdx.x * 256 + threadIdx.x;
    int lane = threadIdx.x & 63;
    int d = (n < N) ? deg_cursor[n] : 0;
    int incl = d;
    for (int s = 1; s < 64; s <<= 1) {
        int t = __shfl_up(incl, s, 64);
        if (lane >= s) incl += t;
    }
    int total = __shfl(incl, 63, 64);
    int base = 0;
    if (lane == 63) base = atomicAdd(counter, total);
    base = __shfl(base, 63, 64);
    int s0 = base + incl - d;
    if (n < N) {
        startv[n] = s0;
        deg_cursor[n] = s0;   // becomes the scatter cursor
    }
}

// ---- fused dispatch: scatter (first S blocks) + GEMM1 (rest) --------------
__global__ __launch_bounds__(512) void k_sg(
    const int* __restrict__ src, const int* __restrict__ dst,
    int* __restrict__ cursor, unsigned short* __restrict__ csr_src,
    const unsigned short* __restrict__ xb,     // [N][128] bf16
    const unsigned short* __restrict__ WE2T,   // [512][128] bf16 (col-major)
    const float* __restrict__ b_edge,          // [256] fp32
    unsigned short* __restrict__ T,            // [N][512]
    int E, int N, int row_tiles, int scat_blocks)
{
    __shared__ unsigned short st[2][16 * 128];
    if ((int)blockIdx.x < scat_blocks) {
        int i = blockIdx.x * 512 + threadIdx.x;
        if (i >= E) return;
        int s = src[i], d = dst[i];
        if ((unsigned)d >= (unsigned)N || (unsigned)s >= (unsigned)N) return;
        int pos = atomicAdd(&cursor[d], 1);
        if ((unsigned)pos < (unsigned)E) csr_src[pos] = (unsigned short)s;
        return;
    }
    int g = blockIdx.x - scat_blocks;
    int gx = g >> 2;                           // row group (8 tiles)
    int gy = g & 3;                            // col quarter (128 cols)

    const int lane = threadIdx.x & 63;
    const int wave = threadIdx.x >> 6;
    const int quad = lane >> 4;
    const int col16 = lane & 15;
    const int lcol = wave * 16 + col16;        // 0..127
    const int col = gy * 128 + lcol;           // 0..511

    float bias = (col < 256) ? b_edge[col] : 0.f;

    short8 bf[4];
    for (int ks = 0; ks < 4; ++ks)
        bf[ks] = *(const short8*)(WE2T + (size_t)col * 128 + ks * 32 + quad * 8);

    const int tid = threadIdx.x;
    const int srow = tid >> 5;                 // 0..15
    const int sc4 = (tid & 31) * 4;            // 0..124

    for (int t = 0; t < 8; ++t) {
        int tile = gx * 8 + t;
        if (tile >= row_tiles) break;          // block-uniform
        int r0 = tile * 16;
        f32x4 acc = {0.f, 0.f, 0.f, 0.f};
        const unsigned short* ap = xb + (size_t)(r0 + col16) * 128 + quad * 8;
        for (int ks = 0; ks < 4; ++ks) {
            short8 a = *(const short8*)(ap + ks * 32);
            acc = __builtin_amdgcn_mfma_f32_16x16x32_bf16(a, bf[ks], acc, 0, 0, 0);
        }
        unsigned short* sb = st[t & 1];
        for (int r = 0; r < 4; ++r)
            sb[(quad * 4 + r) * 128 + lcol] = f2bf(acc[r] + bias);
        __syncthreads();   // one barrier/tile; dbuf makes cross-tile reuse safe
        us4 v = *(const us4*)(sb + srow * 128 + sc4);
        *(us4*)(T + (size_t)(r0 + srow) * 512 + gy * 128 + sc4) = v;
    }
}

// ---- Gather: one wave per node, 4 edges in flight (2 per half-wave) -------
__global__ __launch_bounds__(64) void k_gather(
    unsigned short* __restrict__ T,          // [N][512]: P|Q -> EA over P
    const unsigned short* __restrict__ xb,   // [N][128]
    unsigned short* __restrict__ XA,         // [N][128]
    const int* __restrict__ start, const int* __restrict__ endp,
    const unsigned short* __restrict__ csr_src, int N, int E)
{
    int n = blockIdx.x;
    if (n >= N) return;
    int lane = threadIdx.x;
    int half = lane >> 5;
    int c = lane & 31;
    int c8 = c * 8;
    int c4 = c * 4;

    us8 pv = *(const us8*)(T + (size_t)n * 512 + c8);
    float p[8];
    for (int j = 0; j < 8; ++j) p[j] = bf2f(pv[j]);
    float aE[8] = {0, 0, 0, 0, 0, 0, 0, 0};
    float aX[4] = {0, 0, 0, 0};

    int b = start[n], e = endp[n];
    if (b < 0) b = 0;
    if (e > E) e = E;
    for (int i = b; i < e; i += 4) {
        int i0 = i + half;
        int i1 = i + 2 + half;
        float m0 = (i0 < e) ? 1.f : 0.f;
        float m1 = (i1 < e) ? 1.f : 0.f;
        int idx0 = (i0 < e) ? i0 : b;
        int idx1 = (i1 < e) ? i1 : b;
        int s0 = csr_src[idx0];
        int s1 = csr_src[idx1];
        const unsigned short* tb0 = T + (size_t)s0 * 512;
        const unsigned short* tb1 = T + (size_t)s1 * 512;
        us8 qv0 = *(const us8*)(tb0 + 256 + c8);
        us4 xv0 = *(const us4*)(xb + (size_t)s0 * 128 + c4);
        us8 qv1 = *(const us8*)(tb1 + 256 + c8);
        us4 xv1 = *(const us4*)(xb + (size_t)s1 * 128 + c4);
        for (int j = 0; j < 8; ++j) {
            aE[j] += m0 * fmaxf(p[j] + bf2f(qv0[j]), 0.f);
            aE[j] += m1 * fmaxf(p[j] + bf2f(qv1[j]), 0.f);
        }
        for (int j = 0; j < 4; ++j) {
            aX[j] += m0 * bf2f(xv0[j]);
            aX[j] += m1 * bf2f(xv1[j]);
        }
    }
    for (int j = 0; j < 8; ++j) aE[j] += __shfl_xor(aE[j], 32, 64);
    for (int j = 0; j < 4; ++j) aX[j] += __shfl_xor(aX[j], 32, 64);
    if (half == 0) {
        us8 ev;
        for (int j = 0; j < 8; ++j) ev[j] = f2bf(aE[j]);
        *(us8*)(T + (size_t)n * 512 + c8) = ev;       // EA over own P slot: safe
        us4 xo;
        for (int j = 0; j < 4; ++j) xo[j] = f2bf(aX[j]);
        *(us4*)(XA + (size_t)n * 128 + c4) = xo;
    }
}

// ---- Fused tail: nodes/edges GEMMs + final MLP + sigmoid ------------------
// One wave per 16-row tile; per-wave LDS h-tile [16][392] (C->A layout).
// No __syncthreads (wave-local LDS slice).
__global__ __launch_bounds__(256) void k_tail(
    const unsigned short* __restrict__ T,    // EA in cols 0-255
    const unsigned short* __restrict__ XA,   // [N][128]
    const unsigned short* __restrict__ WnT,  // [256][128] col-major
    const unsigned short* __restrict__ WdT,  // [128][256] col-major
    const unsigned short* __restrict__ Wf1T, // [32][384] col-major
    const float* __restrict__ b_node, const float* __restrict__ b_ed,
    const float* __restrict__ b_f1, const float* __restrict__ W_f2,
    const float* __restrict__ b_f2,
    float* __restrict__ out, int N, int row_tiles)
{
    __shared__ unsigned short hs[4][16 * 392];
    const int wave = threadIdx.x >> 6;
    const int lane = threadIdx.x & 63;
    const int quad = lane >> 4;
    const int col16 = lane & 15;
    int tile = blockIdx.x * 4 + wave;
    if (tile >= row_tiles) return;
    int r0 = tile * 16;
    unsigned short* hw = &hs[wave][0];

    int arow = r0 + col16;
    if (arow >= N) arow = N - 1;              // clamp A-loads; stores guarded

    // nodes = relu(XA @ Wn + b_node) -> LDS cols 0-255
    short8 ax[4];
    {
        const unsigned short* xap = XA + (size_t)arow * 128 + quad * 8;
        for (int ks = 0; ks < 4; ++ks) ax[ks] = *(const short8*)(xap + ks * 32);
    }
    for (int cs = 0; cs < 16; ++cs) {
        int col = cs * 16 + col16;
        const unsigned short* wp = WnT + (size_t)col * 128 + quad * 8;
        f32x4 acc = {0.f, 0.f, 0.f, 0.f};
        for (int ks = 0; ks < 4; ++ks) {
            short8 b = *(const short8*)(wp + ks * 32);
            acc = __builtin_amdgcn_mfma_f32_16x16x32_bf16(ax[ks], b, acc, 0, 0, 0);
        }
        float bias = b_node[col];
        for (int r = 0; r < 4; ++r)
            hw[(quad * 4 + r) * 392 + col] = f2bf(fmaxf(acc[r] + bias, 0.f));
    }

    // edges = relu(EA @ Wd + b_ed) -> LDS cols 256-383
    short8 ae[8];
    {
        const unsigned short* eap = T + (size_t)arow * 512 + quad * 8;
        for (int ks = 0; ks < 8; ++ks) ae[ks] = *(const short8*)(eap + ks * 32);
    }
    for (int cs = 0; cs < 8; ++cs) {
        int col = cs * 16 + col16;
        const unsigned short* wp = WdT + (size_t)col * 256 + quad * 8;
        f32x4 acc = {0.f, 0.f, 0.f, 0.f};
        for (int ks = 0; ks < 8; ++ks) {
            short8 b = *(const short8*)(wp + ks * 32);
            acc = __builtin_amdgcn_mfma_f32_16x16x32_bf16(ae[ks], b, acc, 0, 0, 0);
        }
        float bias = b_ed[col];
        for (int r = 0; r < 4; ++r)
            hw[(quad * 4 + r) * 392 + 256 + col] = f2bf(fmaxf(acc[r] + bias, 0.f));
    }

    // h @ Wf1 (K=384), relu, @W_f2, sigmoid
    f32x4 acc0 = {0.f, 0.f, 0.f, 0.f}, acc1 = {0.f, 0.f, 0.f, 0.f};
    const unsigned short* hp = hw + col16 * 392;
    const unsigned short* wpa = Wf1T + (size_t)col16 * 384;
    const unsigned short* wpb = Wf1T + (size_t)(col16 + 16) * 384;
    for (int ks = 0; ks < 12; ++ks) {
        short8 a = *(const short8*)(hp + ks * 32 + quad * 8);
        short8 ba = *(const short8*)(wpa + ks * 32 + quad * 8);
        short8 bb = *(const short8*)(wpb + ks * 32 + quad * 8);
        acc0 = __builtin_amdgcn_mfma_f32_16x16x32_bf16(a, ba, acc0, 0, 0, 0);
        acc1 = __builtin_amdgcn_mfma_f32_16x16x32_bf16(a, bb, acc1, 0, 0, 0);
    }
    float f1a = b_f1[col16], f1b = b_f1[16 + col16];
    float w2a = W_f2[col16], w2b = W_f2[16 + col16];
    float b2 = b_f2[0];
    float s[4];
    for (int r = 0; r < 4; ++r)
        s[r] = fmaxf(acc0[r] + f1a, 0.f) * w2a + fmaxf(acc1[r] + f1b, 0.f) * w2b;
    for (int m = 1; m < 16; m <<= 1)
        for (int r = 0; r < 4; ++r) s[r] += __shfl_xor(s[r], m, 64);
    if (col16 == 0) {
        int orow = r0 + quad * 4;
        for (int r = 0; r < 4; ++r) {
            if (orow + r < N) {
                float v = s[r] + b2;
                out[orow + r] = 1.f / (1.f + __expf(-v));
            }
        }
    }
}

extern "C" void kernel_launch(void* const* d_in, const int* in_sizes, int n_in,
                              void* d_out, int out_size, void* d_ws, size_t ws_size,
                              hipStream_t stream) {
    const float* x      = (const float*)d_in[0];
    const int*   ei     = (const int*)d_in[1];
    // d_in[2] = e (unused)
    const float* W_node = (const float*)d_in[3];
    const float* b_node = (const float*)d_in[4];
    const float* W_edge = (const float*)d_in[5];
    const float* b_edge = (const float*)d_in[6];
    const float* W_ed   = (const float*)d_in[7];
    const float* b_ed   = (const float*)d_in[8];
    const float* W_f1   = (const float*)d_in[9];
    const float* b_f1   = (const float*)d_in[10];
    const float* W_f2   = (const float*)d_in[11];
    const float* b_f2   = (const float*)d_in[12];

    const int N = in_sizes[0] / 128;
    const int E = in_sizes[1] / 2;
    const int* src = ei;
    const int* dst = ei + E;

    char* ws = (char*)d_ws;
    size_t off = 0;
    auto alloc = [&](size_t bytes) { size_t o = off; off += (bytes + 255) & ~(size_t)255; return o; };
    unsigned short* xb   = (unsigned short*)(ws + alloc((size_t)N * 128 * 2));
    unsigned short* WE2T = (unsigned short*)(ws + alloc(512 * 128 * 2));
    unsigned short* WnT  = (unsigned short*)(ws + alloc(256 * 128 * 2));
    unsigned short* WdT  = (unsigned short*)(ws + alloc(128 * 256 * 2));
    unsigned short* Wf1T = (unsigned short*)(ws + alloc(32 * 384 * 2));
    unsigned short* T    = (unsigned short*)(ws + alloc((size_t)N * 512 * 2));
    unsigned short* XA   = (unsigned short*)(ws + alloc((size_t)N * 128 * 2));
    int* deg_cursor      = (int*)(ws + alloc((size_t)N * 4 + 16));
    int* counter         = deg_cursor + N;
    int* startv          = (int*)(ws + alloc((size_t)N * 4));
    unsigned short* csr  = (unsigned short*)(ws + alloc((size_t)E * 2));

    const int row_tiles   = (N + 15) / 16;
    const int row_groups  = (row_tiles + 7) / 8;
    const int quads       = N * 128 / 4;
    const int nzero       = N + 4;
    const int conv_items  = quads + 143360 + nzero;
    const int scat_blocks = (E + 511) / 512;
    const int gemm_blocks = row_groups * 4;

    k_convert<<<(conv_items + 255) / 256, 256, 0, stream>>>(
        x, W_edge, W_node, W_ed, W_f1, xb, WE2T, WnT, WdT, Wf1T, deg_cursor,
        quads, nzero);
    k_hist<<<(E + 255) / 256, 256, 0, stream>>>(dst, deg_cursor, E, N);
    k_assign<<<(N + 255) / 256, 256, 0, stream>>>(deg_cursor, startv, counter, N);
    k_sg<<<scat_blocks + gemm_blocks, 512, 0, stream>>>(
        src, dst, deg_cursor, csr, xb, WE2T, b_edge, T, E, N, row_tiles, scat_blocks);
    k_gather<<<N, 64, 0, stream>>>(T, xb, XA, startv, deg_cursor, csr, N, E);
    k_tail<<<(row_tiles + 3) / 4, 256, 0, stream>>>(
        T, XA, WnT, WdT, Wf1T, b_node, b_ed, b_f1, W_f2, b_f2,
        (float*)d_out, N, row_tiles);
}

// Round 9
// 306.124 us; speedup vs baseline: 1.1098x; 1.1098x over previous
//
#include <hip/hip_runtime.h>
#include <stdint.h>

// ---------------------------------------------------------------------------
// EdgeNodeGCN on MI355X (gfx950). Inputs fp32, edge_index int32, output fp32.
// Factorization:
//   P[n]  = x[n] @ (Wa - Wb) + b_edge   (Wa = W_edge[0:128], Wb = W_edge[128:256])
//   Q[n]  = x[n] @ Wb
//   msg(e)= relu(P[dst] + Q[src]);  edge_agg[d] = sum msg
//   XA[d] = sum_{e->d} x[src]           (segment_sum commutes with @W_node)
//   nodes = relu(XA @ W_node + b_node); edges = relu(edge_agg @ W_ed + b_ed)
//   out   = sigmoid(relu([nodes|edges] @ W_f1 + b_f1) @ W_f2 + b_f2)
//
// R9 vs R8 (340 us): the wall was ~800K random device atomics (~115us across
// hist+scatter; R8 store/VALU fixes changed nothing -> not store-bound).
//   - CSR replaced by LINKED LIST: one atomicExch per edge; next2[e] packs
//     (src<<32)|prev — coalesced write. hist + assign kernels DELETED.
//   - gather walks chains: half-wave per node (2 chains/wave), 256-thr blocks.
//   - k_sg: gemm/exch blocks interleaved 2:1 for co-residency; LDS stride 132
//     (conflict-free staging; R8 had 800K conflicts at stride 128).
// Dispatches: convert, sg, gather, tail (4).
// ---------------------------------------------------------------------------

typedef short short8 __attribute__((ext_vector_type(8)));
typedef float f32x4 __attribute__((ext_vector_type(4)));
typedef float float4v __attribute__((ext_vector_type(4)));
typedef unsigned short us8 __attribute__((ext_vector_type(8)));
typedef unsigned short us4 __attribute__((ext_vector_type(4)));

__device__ inline float bf2f(unsigned short h) {
    union { unsigned int u; float f; } v;
    v.u = ((unsigned int)h) << 16;
    return v.f;
}
__device__ inline unsigned short f2bf(float f) {
    union { float f; unsigned int u; } v;
    v.f = f;
    unsigned int r = v.u + 0x7FFFu + ((v.u >> 16) & 1u);  // RNE
    return (unsigned short)(r >> 16);
}

// ---- convert x + weights(col-major) -> bf16; head[] = -1 ------------------
__global__ __launch_bounds__(256) void k_convert(
    const float* __restrict__ x, const float* __restrict__ W_edge,
    const float* __restrict__ W_node, const float* __restrict__ W_ed,
    const float* __restrict__ W_f1,
    unsigned short* __restrict__ xb, unsigned short* __restrict__ WE2T,
    unsigned short* __restrict__ WnT, unsigned short* __restrict__ WdT,
    unsigned short* __restrict__ Wf1T, int* __restrict__ head,
    int quads, int N)
{
    int i = blockIdx.x * 256 + threadIdx.x;
    if (i < quads) {
        float4v v = ((const float4v*)x)[i];
        us4 o;
        for (int j = 0; j < 4; ++j) o[j] = f2bf(v[j]);
        ((us4*)xb)[i] = o;
        return;
    }
    int j = i - quads;
    if (j < 65536) {                          // WE2T [512 c][128 k] = [Wa-Wb|Wb]^T
        int c = j & 511, k = j >> 9;
        float v;
        if (c < 256) v = W_edge[k * 256 + c] - W_edge[(k + 128) * 256 + c];
        else         v = W_edge[(k + 128) * 256 + (c - 256)];
        WE2T[c * 128 + k] = f2bf(v);
    } else if (j < 65536 + 32768) {           // WnT [256 c][128 k]
        int t = j - 65536;
        int c = t & 255, k = t >> 8;
        WnT[c * 128 + k] = f2bf(W_node[k * 256 + c]);
    } else if (j < 65536 + 65536) {           // WdT [128 c][256 k]
        int t = j - 65536 - 32768;
        int c = t & 127, k = t >> 7;
        WdT[c * 256 + k] = f2bf(W_ed[k * 128 + c]);
    } else if (j < 143360) {                  // Wf1T [32 c][384 k]
        int t = j - 65536 - 65536;
        int c = t & 31, k = t >> 5;
        Wf1T[c * 384 + k] = f2bf(W_f1[k * 32 + c]);
    } else {
        int t = j - 143360;
        if (t < N) head[t] = -1;
    }
}

// ---- fused dispatch: linked-list build (1/3 of blocks) + GEMM1 (2/3) ------
__global__ __launch_bounds__(512) void k_sg(
    const int* __restrict__ src, const int* __restrict__ dst,
    int* __restrict__ head, unsigned long long* __restrict__ next2,
    const unsigned short* __restrict__ xb,     // [N][128] bf16
    const unsigned short* __restrict__ WE2T,   // [512][128] bf16 col-major
    const float* __restrict__ b_edge,          // [256] fp32
    unsigned short* __restrict__ T,            // [N][512]
    int E, int N, int row_tiles, int scat_blocks, int gemm_blocks)
{
    __shared__ unsigned short st[2][16 * 132];
    int b = blockIdx.x;
    if (b % 3 == 2) {                          // linked-list pass
        int sb_id = b / 3;
        if (sb_id >= scat_blocks) return;
        int i = sb_id * 512 + threadIdx.x;
        if (i >= E) return;
        int s = src[i], d = dst[i];
        if ((unsigned)d >= (unsigned)N || (unsigned)s >= (unsigned)N) return;
        int old = atomicExch(&head[d], i);
        next2[i] = ((unsigned long long)(unsigned)s << 32) | (unsigned)old;
        return;
    }
    int g = b - b / 3;                         // gemm block id
    if (g >= gemm_blocks) return;
    int gx = g >> 2;                           // row group (8 tiles)
    int gy = g & 3;                            // col quarter (128 cols)

    const int lane = threadIdx.x & 63;
    const int wave = threadIdx.x >> 6;
    const int quad = lane >> 4;
    const int col16 = lane & 15;
    const int lcol = wave * 16 + col16;        // 0..127
    const int col = gy * 128 + lcol;           // 0..511

    float bias = (col < 256) ? b_edge[col] : 0.f;

    short8 bf[4];
    for (int ks = 0; ks < 4; ++ks)
        bf[ks] = *(const short8*)(WE2T + (size_t)col * 128 + ks * 32 + quad * 8);

    const int tid = threadIdx.x;
    const int srow = tid >> 5;                 // 0..15
    const int sc4 = (tid & 31) * 4;            // 0..124

    for (int t = 0; t < 8; ++t) {
        int tile = gx * 8 + t;
        if (tile >= row_tiles) break;          // block-uniform
        int r0 = tile * 16;
        f32x4 acc = {0.f, 0.f, 0.f, 0.f};
        const unsigned short* ap = xb + (size_t)(r0 + col16) * 128 + quad * 8;
        for (int ks = 0; ks < 4; ++ks) {
            short8 a = *(const short8*)(ap + ks * 32);
            acc = __builtin_amdgcn_mfma_f32_16x16x32_bf16(a, bf[ks], acc, 0, 0, 0);
        }
        unsigned short* sbuf = st[t & 1];
        for (int r = 0; r < 4; ++r)
            sbuf[(quad * 4 + r) * 132 + lcol] = f2bf(acc[r] + bias);
        __syncthreads();
        us4 v = *(const us4*)(sbuf + srow * 132 + sc4);
        *(us4*)(T + (size_t)(r0 + srow) * 512 + gy * 128 + sc4) = v;
    }
}

// ---- Gather: half-wave per node, chain walk over linked list --------------
__global__ __launch_bounds__(256) void k_gather(
    unsigned short* __restrict__ T,          // [N][512]: P|Q -> EA over P
    const unsigned short* __restrict__ xb,   // [N][128]
    unsigned short* __restrict__ XA,         // [N][128]
    const int* __restrict__ head,
    const unsigned long long* __restrict__ next2, int N)
{
    int wave = threadIdx.x >> 6;
    int lane = threadIdx.x & 63;
    int half = lane >> 5;
    int c = lane & 31;
    int n = blockIdx.x * 8 + wave * 2 + half;
    bool act = n < N;
    int nn = act ? n : N - 1;
    int c8 = c * 8, c4 = c * 4;

    us8 pv = *(const us8*)(T + (size_t)nn * 512 + c8);
    float p[8];
    for (int j = 0; j < 8; ++j) p[j] = bf2f(pv[j]);
    float aE[8] = {0, 0, 0, 0, 0, 0, 0, 0};
    float aX[4] = {0, 0, 0, 0};

    int cur = act ? head[n] : -1;
    while (__any(cur >= 0)) {
        bool v = cur >= 0;
        int safe = v ? cur : 0;
        unsigned long long e2 = next2[safe];   // same addr across half: broadcast
        int s = (int)(e2 >> 32);
        float m = v ? 1.f : 0.f;
        const unsigned short* tb = T + (size_t)s * 512;
        us8 qv = *(const us8*)(tb + 256 + c8);
        us4 xv = *(const us4*)(xb + (size_t)s * 128 + c4);
        for (int j = 0; j < 8; ++j)
            aE[j] += m * fmaxf(p[j] + bf2f(qv[j]), 0.f);
        for (int j = 0; j < 4; ++j)
            aX[j] += m * bf2f(xv[j]);
        cur = v ? (int)(unsigned)(e2 & 0xFFFFFFFFull) : -1;
    }
    if (act) {
        us8 ev;
        for (int j = 0; j < 8; ++j) ev[j] = f2bf(aE[j]);
        *(us8*)(T + (size_t)n * 512 + c8) = ev;       // EA over own P slot: safe
        us4 xo;
        for (int j = 0; j < 4; ++j) xo[j] = f2bf(aX[j]);
        *(us4*)(XA + (size_t)n * 128 + c4) = xo;
    }
}

// ---- Fused tail: nodes/edges GEMMs + final MLP + sigmoid ------------------
// One wave per 16-row tile; per-wave LDS h-tile [16][392] (C->A layout).
__global__ __launch_bounds__(256) void k_tail(
    const unsigned short* __restrict__ T,    // EA in cols 0-255
    const unsigned short* __restrict__ XA,   // [N][128]
    const unsigned short* __restrict__ WnT,  // [256][128] col-major
    const unsigned short* __restrict__ WdT,  // [128][256] col-major
    const unsigned short* __restrict__ Wf1T, // [32][384] col-major
    const float* __restrict__ b_node, const float* __restrict__ b_ed,
    const float* __restrict__ b_f1, const float* __restrict__ W_f2,
    const float* __restrict__ b_f2,
    float* __restrict__ out, int N, int row_tiles)
{
    __shared__ unsigned short hs[4][16 * 392];
    const int wave = threadIdx.x >> 6;
    const int lane = threadIdx.x & 63;
    const int quad = lane >> 4;
    const int col16 = lane & 15;
    int tile = blockIdx.x * 4 + wave;
    if (tile >= row_tiles) return;
    int r0 = tile * 16;
    unsigned short* hw = &hs[wave][0];

    int arow = r0 + col16;
    if (arow >= N) arow = N - 1;

    short8 ax[4];
    {
        const unsigned short* xap = XA + (size_t)arow * 128 + quad * 8;
        for (int ks = 0; ks < 4; ++ks) ax[ks] = *(const short8*)(xap + ks * 32);
    }
    for (int cs = 0; cs < 16; ++cs) {
        int col = cs * 16 + col16;
        const unsigned short* wp = WnT + (size_t)col * 128 + quad * 8;
        f32x4 acc = {0.f, 0.f, 0.f, 0.f};
        for (int ks = 0; ks < 4; ++ks) {
            short8 b = *(const short8*)(wp + ks * 32);
            acc = __builtin_amdgcn_mfma_f32_16x16x32_bf16(ax[ks], b, acc, 0, 0, 0);
        }
        float bias = b_node[col];
        for (int r = 0; r < 4; ++r)
            hw[(quad * 4 + r) * 392 + col] = f2bf(fmaxf(acc[r] + bias, 0.f));
    }

    short8 ae[8];
    {
        const unsigned short* eap = T + (size_t)arow * 512 + quad * 8;
        for (int ks = 0; ks < 8; ++ks) ae[ks] = *(const short8*)(eap + ks * 32);
    }
    for (int cs = 0; cs < 8; ++cs) {
        int col = cs * 16 + col16;
        const unsigned short* wp = WdT + (size_t)col * 256 + quad * 8;
        f32x4 acc = {0.f, 0.f, 0.f, 0.f};
        for (int ks = 0; ks < 8; ++ks) {
            short8 b = *(const short8*)(wp + ks * 32);
            acc = __builtin_amdgcn_mfma_f32_16x16x32_bf16(ae[ks], b, acc, 0, 0, 0);
        }
        float bias = b_ed[col];
        for (int r = 0; r < 4; ++r)
            hw[(quad * 4 + r) * 392 + 256 + col] = f2bf(fmaxf(acc[r] + bias, 0.f));
    }

    f32x4 acc0 = {0.f, 0.f, 0.f, 0.f}, acc1 = {0.f, 0.f, 0.f, 0.f};
    const unsigned short* hp = hw + col16 * 392;
    const unsigned short* wpa = Wf1T + (size_t)col16 * 384;
    const unsigned short* wpb = Wf1T + (size_t)(col16 + 16) * 384;
    for (int ks = 0; ks < 12; ++ks) {
        short8 a = *(const short8*)(hp + ks * 32 + quad * 8);
        short8 ba = *(const short8*)(wpa + ks * 32 + quad * 8);
        short8 bb = *(const short8*)(wpb + ks * 32 + quad * 8);
        acc0 = __builtin_amdgcn_mfma_f32_16x16x32_bf16(a, ba, acc0, 0, 0, 0);
        acc1 = __builtin_amdgcn_mfma_f32_16x16x32_bf16(a, bb, acc1, 0, 0, 0);
    }
    float f1a = b_f1[col16], f1b = b_f1[16 + col16];
    float w2a = W_f2[col16], w2b = W_f2[16 + col16];
    float b2 = b_f2[0];
    float s[4];
    for (int r = 0; r < 4; ++r)
        s[r] = fmaxf(acc0[r] + f1a, 0.f) * w2a + fmaxf(acc1[r] + f1b, 0.f) * w2b;
    for (int m = 1; m < 16; m <<= 1)
        for (int r = 0; r < 4; ++r) s[r] += __shfl_xor(s[r], m, 64);
    if (col16 == 0) {
        int orow = r0 + quad * 4;
        for (int r = 0; r < 4; ++r) {
            if (orow + r < N) {
                float v = s[r] + b2;
                out[orow + r] = 1.f / (1.f + __expf(-v));
            }
        }
    }
}

extern "C" void kernel_launch(void* const* d_in, const int* in_sizes, int n_in,
                              void* d_out, int out_size, void* d_ws, size_t ws_size,
                              hipStream_t stream) {
    const float* x      = (const float*)d_in[0];
    const int*   ei     = (const int*)d_in[1];
    // d_in[2] = e (unused)
    const float* W_node = (const float*)d_in[3];
    const float* b_node = (const float*)d_in[4];
    const float* W_edge = (const float*)d_in[5];
    const float* b_edge = (const float*)d_in[6];
    const float* W_ed   = (const float*)d_in[7];
    const float* b_ed   = (const float*)d_in[8];
    const float* W_f1   = (const float*)d_in[9];
    const float* b_f1   = (const float*)d_in[10];
    const float* W_f2   = (const float*)d_in[11];
    const float* b_f2   = (const float*)d_in[12];

    const int N = in_sizes[0] / 128;
    const int E = in_sizes[1] / 2;
    const int* src = ei;
    const int* dst = ei + E;

    char* ws = (char*)d_ws;
    size_t off = 0;
    auto alloc = [&](size_t bytes) { size_t o = off; off += (bytes + 255) & ~(size_t)255; return o; };
    unsigned short* xb   = (unsigned short*)(ws + alloc((size_t)N * 128 * 2));
    unsigned short* WE2T = (unsigned short*)(ws + alloc(512 * 128 * 2));
    unsigned short* WnT  = (unsigned short*)(ws + alloc(256 * 128 * 2));
    unsigned short* WdT  = (unsigned short*)(ws + alloc(128 * 256 * 2));
    unsigned short* Wf1T = (unsigned short*)(ws + alloc(32 * 384 * 2));
    unsigned short* T    = (unsigned short*)(ws + alloc((size_t)N * 512 * 2));
    unsigned short* XA   = (unsigned short*)(ws + alloc((size_t)N * 128 * 2));
    int* head            = (int*)(ws + alloc((size_t)N * 4));
    unsigned long long* next2 = (unsigned long long*)(ws + alloc((size_t)E * 8));

    const int row_tiles   = (N + 15) / 16;
    const int row_groups  = (row_tiles + 7) / 8;
    const int quads       = N * 128 / 4;
    const int conv_items  = quads + 143360 + N;
    const int scat_blocks = (E + 511) / 512;
    const int gemm_blocks = row_groups * 4;
    int grid3 = scat_blocks * 3;
    int need_g = ((gemm_blocks + 1) / 2) * 3;
    if (need_g > grid3) grid3 = need_g;

    k_convert<<<(conv_items + 255) / 256, 256, 0, stream>>>(
        x, W_edge, W_node, W_ed, W_f1, xb, WE2T, WnT, WdT, Wf1T, head,
        quads, N);
    k_sg<<<grid3, 512, 0, stream>>>(
        src, dst, head, next2, xb, WE2T, b_edge, T, E, N, row_tiles,
        scat_blocks, gemm_blocks);
    k_gather<<<(N + 7) / 8, 256, 0, stream>>>(T, xb, XA, head, next2, N);
    k_tail<<<(row_tiles + 3) / 4, 256, 0, stream>>>(
        T, XA, WnT, WdT, Wf1T, b_node, b_ed, b_f1, W_f2, b_f2,
        (float*)d_out, N, row_tiles);
}